// Round 5
// baseline (1251.422 us; speedup 1.0000x reference)
//
#include <hip/hip_runtime.h>

// Elman ReLU RNN, fused persistent kernel. Split-K-4 math + flag handshake,
// with the sync round-trip HIDDEN under own-half compute via a half-permuted
// h layout.
//
// B=256 blocks (1 batch per CU), 256 threads (4 waves):
//   waves 0-1: h-update. Wave A owns rows 0..57, wave B rows 58..115.
//              h storage is permuted so each 32-col chunk = 16 wave-A floats
//              then 16 wave-B floats. Per step each lane: peek other wave's
//              flag, read+FMA its OWN 16 cols (self-written, no sync needed),
//              then spin if the peek missed, read+FMA the other 16 cols,
//              quad-reduce (DPP), write h, bump flag. The cross-wave LDS
//              round-trip overlaps the own-half work instead of adding.
//   wave  2  : fc, lagging one superstep (u in [8s-8, 8s-1], barrier-publ.).
//   wave  3  : xp producer, leading one superstep (tau in [8s+8, 8s+15]),
//              + x streaming: global -> 4-deep reg ring -> LDS ring.
// Full (lgkm-only) barrier once per 8 steps. Rings: h depth 16 (h-wave skew
// <=1 by poll; fc lag 8 disjoint mod 16), xp depth 16 (lead 8 disjoint).
//
// h storage permutation (chunk-padded 36 floats per 32-col chunk):
//   A-row r (r<58):   float index 36*(r>>4) + (r&15)
//   B-row r (r>=58):  rr=r-58; float index 36*(rr>>4) + 16 + (rr&15)
// Column j of chunk k (j<16): actual col 16k+j (pad if >=58)
//                    (j>=16): actual col 58+16k+(j-16) (pad if 16k+j-16>=58)
// Pad positions are zeroed at init for ALL ring slots (0 * garbage hazard).

namespace {
constexpr int kB = 256;
constexpr int kT = 2048;
constexpr int kI = 50;
constexpr int kH = 116;
constexpr int kO = 50;
constexpr int kSS = 8;    // steps per superstep (barrier period)
constexpr int kHD = 16;   // h ring depth
constexpr int kXPD = 16;  // xp ring depth
}

struct Smem {
  alignas(16) float h[kHD][144];    // permuted h ring, slot t&15
  alignas(16) float xp[kXPD][128];  // xp ring, natural row order, slot t&15
  alignas(16) float xr[4][52];      // x ring, slot tau&3 (wave-3 private)
  int flags[2];                     // per-h-wave completed-step counters
};

__device__ __forceinline__ void sync_lds() {
  // Workgroup barrier draining LDS only; vmcnt stays in flight so the global
  // x prefetch and fc output stores pipeline across supersteps.
  __asm__ __volatile__("s_waitcnt lgkmcnt(0)\n\ts_barrier" ::: "memory");
}

__device__ __forceinline__ void wait_flag(const volatile int* f, int want) {
  while (__builtin_amdgcn_readfirstlane(*f) < want) {}
  __asm__ __volatile__("" ::: "memory");
}

// Quad butterfly adds via DPP quad_perm: VALU-only, no LDS pipe traffic.
__device__ __forceinline__ float qadd1(float v) {  // + lane^1
  return v + __int_as_float(__builtin_amdgcn_update_dpp(
                 0, __float_as_int(v), 0xB1, 0xF, 0xF, true));
}
__device__ __forceinline__ float qadd2(float v) {  // + lane^2
  return v + __int_as_float(__builtin_amdgcn_update_dpp(
                 0, __float_as_int(v), 0x4E, 0xF, 0xF, true));
}

// One h step with overlapped handshake. OWN_OFF = 0 (wave A) / 4 (wave B):
// float4 offset of this wave's self-written half inside its 8-float4 chunk.
template <int OWN_OFF>
__device__ __forceinline__ void h_step2(Smem& sm, int t, const float (&w)[4][32],
                                        int k, int rowk, int hwr, bool wvalid,
                                        bool need_poll, const volatile int* oth,
                                        volatile int* my, int ln) {
  int fl = 0;
  if (need_poll) fl = __builtin_amdgcn_readfirstlane(*oth);  // peek, issued 1st
  const float xpv = sm.xp[t & (kXPD - 1)][rowk];
  const float4* hp4 = (const float4*)sm.h[(t + kHD - 1) & (kHD - 1)];
  float s[4][4];
#pragma unroll
  for (int p = 0; p < 4; ++p) {
    s[p][0] = 0.f; s[p][1] = 0.f; s[p][2] = 0.f; s[p][3] = 0.f;
  }
  {  // Phase 0: own half (written by this wave at step t-1; in-wave ordered).
    float4 hc[4];
#pragma unroll
    for (int i = 0; i < 4; ++i) hc[i] = hp4[9 * k + OWN_OFF + i];
#pragma unroll
    for (int p = 0; p < 4; ++p) {
#pragma unroll
      for (int i = 0; i < 4; ++i) {
        const float4 v = hc[i];
        constexpr int B = 4 * OWN_OFF;
        s[p][0] = fmaf(w[p][B + 4 * i + 0], v.x, s[p][0]);
        s[p][1] = fmaf(w[p][B + 4 * i + 1], v.y, s[p][1]);
        s[p][2] = fmaf(w[p][B + 4 * i + 2], v.z, s[p][2]);
        s[p][3] = fmaf(w[p][B + 4 * i + 3], v.w, s[p][3]);
      }
    }
  }
  if (need_poll && fl < t - 1) wait_flag(oth, t - 1);
  __asm__ __volatile__("" ::: "memory");  // other-half reads stay below poll
  {  // Phase 1: other wave's half.
    constexpr int OO = 4 - OWN_OFF;
    float4 hc[4];
#pragma unroll
    for (int i = 0; i < 4; ++i) hc[i] = hp4[9 * k + OO + i];
#pragma unroll
    for (int p = 0; p < 4; ++p) {
#pragma unroll
      for (int i = 0; i < 4; ++i) {
        const float4 v = hc[i];
        constexpr int B = 4 * OO;
        s[p][0] = fmaf(w[p][B + 4 * i + 0], v.x, s[p][0]);
        s[p][1] = fmaf(w[p][B + 4 * i + 1], v.y, s[p][1]);
        s[p][2] = fmaf(w[p][B + 4 * i + 2], v.z, s[p][2]);
        s[p][3] = fmaf(w[p][B + 4 * i + 3], v.w, s[p][3]);
      }
    }
  }
  float res = 0.f;
#pragma unroll
  for (int p = 0; p < 4; ++p) {
    float c = (s[p][0] + s[p][1]) + (s[p][2] + s[p][3]);
    c = qadd2(qadd1(c));  // quad total, bit-identical in all 4 lanes
    res = (k == p) ? c : res;
  }
  res += xpv;
  res = res > 0.f ? res : 0.f;
  if (wvalid) sm.h[t & (kHD - 1)][hwr] = res;
  __asm__ __volatile__("" ::: "memory");  // h-write ordered before flag bump
  if (ln == 0) *my = t;
}

// fc for h[u] (ring slot u&15): full-chunk split-K-4, weights permuted to
// match the h layout. Runs only after the superstep barrier (h published).
__device__ __forceinline__ void fc_step(Smem& sm, int u, const float (&w)[4][32],
                                        int k, int rowk, float bfc,
                                        float* __restrict__ ob) {
  const float4* hp4 = (const float4*)sm.h[u & (kHD - 1)];
  float4 hc[8];
#pragma unroll
  for (int i = 0; i < 8; ++i) hc[i] = hp4[9 * k + i];
  float res = 0.f;
#pragma unroll
  for (int p = 0; p < 4; ++p) {
    float s0 = 0.f, s1 = 0.f, s2 = 0.f, s3 = 0.f;
#pragma unroll
    for (int i = 0; i < 8; ++i) {
      const float4 v = hc[i];
      s0 = fmaf(w[p][4 * i + 0], v.x, s0);
      s1 = fmaf(w[p][4 * i + 1], v.y, s1);
      s2 = fmaf(w[p][4 * i + 2], v.z, s2);
      s3 = fmaf(w[p][4 * i + 3], v.w, s3);
    }
    float c = (s0 + s1) + (s2 + s3);
    c = qadd2(qadd1(c));
    res = (k == p) ? c : res;
  }
  res += bfc;
  if (rowk < kO) ob[(size_t)u * kO + rowk] = res;
}

__device__ __forceinline__ void xp_step(Smem& sm, int xs, int slot,
                                        const float (&wi0)[kI],
                                        const float (&wi1)[kI],
                                        float bias0, float bias1, int ln) {
  const float4* xq = (const float4*)sm.xr[xs];
  float s00 = 0.f, s01 = 0.f, s02 = 0.f, s03 = 0.f;
  float s10 = 0.f, s11 = 0.f, s12 = 0.f, s13 = 0.f;
#pragma unroll
  for (int i = 0; i < 12; ++i) {
    float4 v = xq[i];
    s00 = fmaf(wi0[4 * i + 0], v.x, s00);
    s01 = fmaf(wi0[4 * i + 1], v.y, s01);
    s02 = fmaf(wi0[4 * i + 2], v.z, s02);
    s03 = fmaf(wi0[4 * i + 3], v.w, s03);
    s10 = fmaf(wi1[4 * i + 0], v.x, s10);
    s11 = fmaf(wi1[4 * i + 1], v.y, s11);
    s12 = fmaf(wi1[4 * i + 2], v.z, s12);
    s13 = fmaf(wi1[4 * i + 3], v.w, s13);
  }
  float2 vt = ((const float2*)sm.xr[xs])[24];  // elements 48,49
  s00 = fmaf(wi0[48], vt.x, s00);
  s01 = fmaf(wi0[49], vt.y, s01);
  s10 = fmaf(wi1[48], vt.x, s10);
  s11 = fmaf(wi1[49], vt.y, s11);
  sm.xp[slot][ln] = bias0 + ((s00 + s01) + (s02 + s03));
  if (ln < kH - 64) sm.xp[slot][ln + 64] = bias1 + ((s10 + s11) + (s12 + s13));
}

__launch_bounds__(256, 1)
__global__ void rnn_fused(const float* __restrict__ x,
                          const float* __restrict__ W_ih,
                          const float* __restrict__ b_ih,
                          const float* __restrict__ W_hh,
                          const float* __restrict__ b_hh,
                          const float* __restrict__ W_fc,
                          const float* __restrict__ b_fc,
                          float* __restrict__ out) {
  __shared__ Smem sm;
  const int tid = threadIdx.x;
  const int wv = tid >> 6;
  const int ln = tid & 63;
  const int b = blockIdx.x;
  const float* xb = x + (size_t)b * (kT * kI);
  float* ob = out + (size_t)b * (kT * kO);

  float w[4][32];          // waves 0-2: per-lane weight tile (chunk k, 4 rows)
  float wi0[kI], wi1[kI];  // wave 3: W_ih rows ln, ln+64
  float bias0 = 0.f, bias1 = 0.f, bfc = 0.f;
  float xrv[4] = {0.f, 0.f, 0.f, 0.f};  // x prefetch regs, xrv[q] -> ring slot q

  const int k = ln & 3;    // storage-column chunk [32k, 32k+32)
  const int rl = ln >> 2;  // local row 0..15
  int rowk = 0, hwr = 0;   // kept row after quad reduce; permuted write index
  bool wvalid = false;

  if (wv < 2) {
    const int rbase = 58 * wv;
    rowk = rbase + rl + 16 * k;
    wvalid = (rl + 16 * k) < 58;
    hwr = 36 * k + (wv == 0 ? rl : 16 + rl);  // permuted position of rowk
#pragma unroll
    for (int p = 0; p < 4; ++p) {
      const int rloc = rl + 16 * p;
      const bool vr = rloc < 58;
      const size_t r = rbase + (vr ? rloc : 0);
#pragma unroll
      for (int j = 0; j < 32; ++j) {
        const int cc = 16 * k + (j < 16 ? j : j - 16);
        const bool cv = cc < 58;
        const int ca = (j < 16) ? cc : 58 + cc;  // permuted col -> actual col
        w[p][j] = (vr && cv) ? W_hh[r * kH + ca] : 0.f;
      }
    }
  } else if (wv == 2) {
    rowk = rl + 16 * k;
#pragma unroll
    for (int p = 0; p < 4; ++p) {
      const int rloc = rl + 16 * p;
      const bool vr = rloc < kO;
      const size_t r = vr ? rloc : 0;
#pragma unroll
      for (int j = 0; j < 32; ++j) {
        const int cc = 16 * k + (j < 16 ? j : j - 16);
        const bool cv = cc < 58;
        const int ca = (j < 16) ? cc : 58 + cc;
        w[p][j] = (vr && cv) ? W_fc[r * kH + ca] : 0.f;
      }
    }
    bfc = (rowk < kO) ? b_fc[rowk] : 0.f;
  } else {
    {
      const float2* wr = (const float2*)(W_ih + ln * kI);  // 200B rows: 8B aligned
#pragma unroll
      for (int i = 0; i < kI / 2; ++i) {
        float2 v = wr[i]; wi0[2 * i] = v.x; wi0[2 * i + 1] = v.y;
      }
      bias0 = b_ih[ln] + b_hh[ln];
    }
    if (ln < kH - 64) {
      const float2* wr = (const float2*)(W_ih + (ln + 64) * kI);
#pragma unroll
      for (int i = 0; i < kI / 2; ++i) {
        float2 v = wr[i]; wi1[2 * i] = v.x; wi1[2 * i + 1] = v.y;
      }
      bias1 = b_ih[ln + 64] + b_hh[ln + 64];
    } else {
#pragma unroll
      for (int i = 0; i < kI; ++i) wi1[i] = 0.f;
    }
    if (ln < kI) {
      // Ring invariant at step tau: slots tau&3, (tau+1)&3 hold x[tau],
      // x[tau+1]; xrv[q] holds the x destined for slot q.
      sm.xr[0][ln] = xb[0 * kI + ln];
      sm.xr[1][ln] = xb[1 * kI + ln];
      xrv[2] = xb[2 * kI + ln];
      xrv[3] = xb[3 * kI + ln];
      xrv[0] = xb[4 * kI + ln];
      xrv[1] = xb[5 * kI + ln];
    }
  }
  // Zero the ENTIRE h ring: h(-1)=0 at slot 15, and all pad positions in all
  // slots must be 0 forever (they multiply zero weights; 0*garbage = hazard).
  for (int z = tid; z < kHD * 144; z += 256) ((float*)sm.h)[z] = 0.f;
  if (tid == 0) { sm.flags[0] = -1; sm.flags[1] = -1; }
  sync_lds();  // barrier: init published

  if (wv < 2) __builtin_amdgcn_s_setprio(2);  // recurrence waves win DS arb.

  // xp prologue: tau = 0..7 fills xp slots 0..7 so h can start at t=0.
  if (wv == 3) {
#pragma unroll
    for (int j = 0; j < kSS; ++j) {
      xp_step(sm, j & 3, j & (kXPD - 1), wi0, wi1, bias0, bias1, ln);
      if (ln < kI) {
        sm.xr[(j + 2) & 3][ln] = xrv[(j + 2) & 3];
        const int tf = j + 6;  // <= 13, no clamp needed
        xrv[(j + 2) & 3] = xb[(size_t)tf * kI + ln];
      }
    }
  }
  sync_lds();  // barrier: xp[0..7] published

  volatile int* my = (volatile int*)&sm.flags[wv & 1];
  const volatile int* oth = (const volatile int*)&sm.flags[1 - (wv & 1)];

#pragma unroll 1
  for (int s = 0; s < kT / kSS; ++s) {
    if (wv == 0) {
      const int t0 = kSS * s;
#pragma unroll
      for (int j = 0; j < kSS; ++j)
        h_step2<0>(sm, t0 + j, w, k, rowk, hwr, wvalid, j > 0, oth, my, ln);
    } else if (wv == 1) {
      const int t0 = kSS * s;
#pragma unroll
      for (int j = 0; j < kSS; ++j)
        h_step2<4>(sm, t0 + j, w, k, rowk, hwr, wvalid, j > 0, oth, my, ln);
    } else if (wv == 2) {
      // Lag one superstep: u in [8s-8, 8s-1]; all h[u] barrier-published.
      if (s > 0) {
        const int u0 = kSS * (s - 1);
#pragma unroll
        for (int j = 0; j < kSS; ++j)
          fc_step(sm, u0 + j, w, k, rowk, bfc, ob);
      }
    } else {
      // Lead one superstep: tau in [8s+8, 8s+15]; slots disjoint (mod 16)
      // from the h-waves' reads this superstep.
      if (s < kT / kSS - 1) {
        const int tau0 = kSS * s + kSS;
#pragma unroll
        for (int j = 0; j < kSS; ++j) {
          const int tau = tau0 + j;
          xp_step(sm, j & 3, tau & (kXPD - 1), wi0, wi1, bias0, bias1, ln);
          if (ln < kI) {
            sm.xr[(j + 2) & 3][ln] = xrv[(j + 2) & 3];  // (tau+2)&3 == (j+2)&3
            int tf = tau + 6; tf = tf < kT ? tf : kT - 1;
            xrv[(j + 2) & 3] = xb[(size_t)tf * kI + ln];
          }
        }
      }
    }
    sync_lds();  // one barrier per 8 steps
  }

  // fc epilogue: u = 2040..2047 (published by the final barrier).
  if (wv == 2) {
#pragma unroll
    for (int j = 0; j < kSS; ++j)
      fc_step(sm, kT - kSS + j, w, k, rowk, bfc, ob);
  }
}

extern "C" void kernel_launch(void* const* d_in, const int* in_sizes, int n_in,
                              void* d_out, int out_size, void* d_ws, size_t ws_size,
                              hipStream_t stream) {
  (void)in_sizes; (void)n_in; (void)d_ws; (void)ws_size; (void)out_size;
  const float* x    = (const float*)d_in[0];
  const float* W_ih = (const float*)d_in[1];
  const float* b_ih = (const float*)d_in[2];
  const float* W_hh = (const float*)d_in[3];
  const float* b_hh = (const float*)d_in[4];
  const float* W_fc = (const float*)d_in[5];
  const float* b_fc = (const float*)d_in[6];
  float* out = (float*)d_out;
  rnn_fused<<<dim3(kB), dim3(256), 0, stream>>>(x, W_ih, b_ih, W_hh, b_hh,
                                                W_fc, b_fc, out);
}

// Round 6
// 1076.009 us; speedup vs baseline: 1.1630x; 1.1630x over previous
//
#include <hip/hip_runtime.h>

// Elman ReLU RNN, fused persistent kernel. Round-4 structure (split-K-4,
// flag handshake, superstep barriers) + two changes:
//  (a) seqlock-style SPECULATIVE h read: issue flag-read FIRST, then all
//      data reads, check flag after. DS ops execute in wave order, and the
//      producer writes h before flag, so flag>=t-1 => data reads are fresh.
//      Hit: sync round-trip fully hidden under the data loads. Miss (leading
//      wave only): spin + re-read.
//  (b) xp input broadcast via v_readlane from a register x-ring instead of
//      bouncing x through LDS (removes 13 uniform ds_read_b128/step + ring
//      writes from the shared LDS pipe; readlanes run on wave 3's own SIMD).
//
// B=256 blocks (1 batch per CU), 256 threads (4 waves):
//   waves 0-1: h-update, split-K-4 (lane: chunk k=ln&3, rows rl+16p, offset
//              58*wv). Natural chunk-padded h layout (36 floats / 32-chunk).
//   wave  2  : fc, lagging one superstep (u in [8s-8, 8s-1], barrier-publ.).
//   wave  3  : xp producer, leading one superstep (tau in [8s+8, 8s+15]);
//              x held in a 4-deep register ring, broadcast via readlane.
// Full (lgkm-only) barrier once per 8 steps. Rings: h depth 16 (h-wave skew
// <=1 by handshake; fc lag 8 disjoint mod 16), xp depth 16 (lead 8 disjoint).

namespace {
constexpr int kB = 256;
constexpr int kT = 2048;
constexpr int kI = 50;
constexpr int kH = 116;
constexpr int kO = 50;
constexpr int kSS = 8;    // steps per superstep (barrier period)
constexpr int kHD = 16;   // h ring depth
constexpr int kXPD = 16;  // xp ring depth
}

struct Smem {
  // h element e of step t lives at h[t&15][36*(e>>5) + (e&31)] (chunk-padded:
  // chunk k = float4 index 9k; 4 distinct chunk addresses in one wave
  // instruction hit disjoint bank groups).
  alignas(16) float h[kHD][144];    // 9216 B
  alignas(16) float xp[kXPD][128];  // 8192 B
  int flags[2];                     // per-h-wave completed-step counters
};

__device__ __forceinline__ void sync_lds() {
  // Workgroup barrier draining LDS only; vmcnt stays in flight so the global
  // x prefetch and fc output stores pipeline across supersteps.
  __asm__ __volatile__("s_waitcnt lgkmcnt(0)\n\ts_barrier" ::: "memory");
}

// Quad butterfly adds via DPP quad_perm: VALU-only, no LDS pipe traffic.
__device__ __forceinline__ float qadd1(float v) {  // + lane^1
  return v + __int_as_float(__builtin_amdgcn_update_dpp(
                 0, __float_as_int(v), 0xB1, 0xF, 0xF, true));
}
__device__ __forceinline__ float qadd2(float v) {  // + lane^2
  return v + __int_as_float(__builtin_amdgcn_update_dpp(
                 0, __float_as_int(v), 0x4E, 0xF, 0xF, true));
}

// h-update step t with speculative handshake. Reads xp[t&15], h[(t-1)&15];
// writes h[t&15], bumps own flag. Arithmetic identical to rounds 3/4.
__device__ __forceinline__ void h_step(Smem& sm, int t, const float (&w)[4][32],
                                       int k, int rowk, int hwr, bool wvalid,
                                       bool need_poll,
                                       const volatile int* oth,
                                       volatile int* my, int ln) {
  const float4* hp4 = (const float4*)sm.h[(t + kHD - 1) & (kHD - 1)];
  int fl = 0;
  if (need_poll) {
    fl = *oth;  // FIRST DS op of the step (seqlock order: flag before data)
    __asm__ __volatile__("" ::: "memory");  // pin data reads after flag read
  }
  const float xpv = sm.xp[t & (kXPD - 1)][rowk];
  float4 hc[8];
#pragma unroll
  for (int i = 0; i < 8; ++i) hc[i] = hp4[9 * k + i];
  if (need_poll && __builtin_amdgcn_readfirstlane(fl) < t - 1) {
    // Speculation miss (this wave is leading): spin, then re-read h.
    while (__builtin_amdgcn_readfirstlane(*oth) < t - 1) {}
    __asm__ __volatile__("" ::: "memory");  // force fresh re-reads
#pragma unroll
    for (int i = 0; i < 8; ++i) hc[i] = hp4[9 * k + i];
  }
  float res = 0.f;
#pragma unroll
  for (int p = 0; p < 4; ++p) {
    float s0 = 0.f, s1 = 0.f, s2 = 0.f, s3 = 0.f;
#pragma unroll
    for (int i = 0; i < 8; ++i) {
      const float4 v = hc[i];
      s0 = fmaf(w[p][4 * i + 0], v.x, s0);
      s1 = fmaf(w[p][4 * i + 1], v.y, s1);
      s2 = fmaf(w[p][4 * i + 2], v.z, s2);
      s3 = fmaf(w[p][4 * i + 3], v.w, s3);
    }
    float c = (s0 + s1) + (s2 + s3);
    c = qadd2(qadd1(c));  // quad total, bit-identical in all 4 lanes
    res = (k == p) ? c : res;
  }
  res += xpv;
  res = res > 0.f ? res : 0.f;
  if (wvalid) sm.h[t & (kHD - 1)][hwr] = res;
  __asm__ __volatile__("" ::: "memory");  // h-write ordered before flag bump
  if (ln == 0) *my = t;
}

// fc for h[u] (ring slot u&15): split-K-4, global store. Runs only on
// barrier-published slots.
__device__ __forceinline__ void fc_step(Smem& sm, int u, const float (&w)[4][32],
                                        int k, int rowk, float bfc,
                                        float* __restrict__ ob) {
  const float4* hp4 = (const float4*)sm.h[u & (kHD - 1)];
  float4 hc[8];
#pragma unroll
  for (int i = 0; i < 8; ++i) hc[i] = hp4[9 * k + i];
  float res = 0.f;
#pragma unroll
  for (int p = 0; p < 4; ++p) {
    float s0 = 0.f, s1 = 0.f, s2 = 0.f, s3 = 0.f;
#pragma unroll
    for (int i = 0; i < 8; ++i) {
      const float4 v = hc[i];
      s0 = fmaf(w[p][4 * i + 0], v.x, s0);
      s1 = fmaf(w[p][4 * i + 1], v.y, s1);
      s2 = fmaf(w[p][4 * i + 2], v.z, s2);
      s3 = fmaf(w[p][4 * i + 3], v.w, s3);
    }
    float c = (s0 + s1) + (s2 + s3);
    c = qadd2(qadd1(c));
    res = (k == p) ? c : res;
  }
  res += bfc;
  if (rowk < kO) ob[(size_t)u * kO + rowk] = res;
}

// xp step via readlane broadcast: xv holds x[tau][ln] in lanes 0..49.
// Same values, same chain structure (element j -> chain j&3) as before.
__device__ __forceinline__ void xp_step_rl(Smem& sm, int slot, float xv,
                                           const float (&wi0)[kI],
                                           const float (&wi1)[kI],
                                           float bias0, float bias1, int ln) {
  const int xvi = __float_as_int(xv);
  float s00 = 0.f, s01 = 0.f, s02 = 0.f, s03 = 0.f;
  float s10 = 0.f, s11 = 0.f, s12 = 0.f, s13 = 0.f;
#pragma unroll
  for (int i = 0; i < 12; ++i) {
    const float x0 = __int_as_float(__builtin_amdgcn_readlane(xvi, 4 * i + 0));
    const float x1 = __int_as_float(__builtin_amdgcn_readlane(xvi, 4 * i + 1));
    const float x2 = __int_as_float(__builtin_amdgcn_readlane(xvi, 4 * i + 2));
    const float x3 = __int_as_float(__builtin_amdgcn_readlane(xvi, 4 * i + 3));
    s00 = fmaf(wi0[4 * i + 0], x0, s00);
    s01 = fmaf(wi0[4 * i + 1], x1, s01);
    s02 = fmaf(wi0[4 * i + 2], x2, s02);
    s03 = fmaf(wi0[4 * i + 3], x3, s03);
    s10 = fmaf(wi1[4 * i + 0], x0, s10);
    s11 = fmaf(wi1[4 * i + 1], x1, s11);
    s12 = fmaf(wi1[4 * i + 2], x2, s12);
    s13 = fmaf(wi1[4 * i + 3], x3, s13);
  }
  const float x48 = __int_as_float(__builtin_amdgcn_readlane(xvi, 48));
  const float x49 = __int_as_float(__builtin_amdgcn_readlane(xvi, 49));
  s00 = fmaf(wi0[48], x48, s00);
  s01 = fmaf(wi0[49], x49, s01);
  s10 = fmaf(wi1[48], x48, s10);
  s11 = fmaf(wi1[49], x49, s11);
  sm.xp[slot][ln] = bias0 + ((s00 + s01) + (s02 + s03));
  if (ln < kH - 64) sm.xp[slot][ln + 64] = bias1 + ((s10 + s11) + (s12 + s13));
}

__launch_bounds__(256, 1)
__global__ void rnn_fused(const float* __restrict__ x,
                          const float* __restrict__ W_ih,
                          const float* __restrict__ b_ih,
                          const float* __restrict__ W_hh,
                          const float* __restrict__ b_hh,
                          const float* __restrict__ W_fc,
                          const float* __restrict__ b_fc,
                          float* __restrict__ out) {
  __shared__ Smem sm;
  const int tid = threadIdx.x;
  const int wv = tid >> 6;
  const int ln = tid & 63;
  const int b = blockIdx.x;
  const float* xb = x + (size_t)b * (kT * kI);
  float* ob = out + (size_t)b * (kT * kO);

  float w[4][32];          // waves 0-2: per-lane weight tile (chunk k, 4 rows)
  float wi0[kI], wi1[kI];  // wave 3: W_ih rows ln, ln+64
  float bias0 = 0.f, bias1 = 0.f, bfc = 0.f;
  float xrv[4] = {0.f, 0.f, 0.f, 0.f};  // x register ring: xrv[q] = x[tau],
                                        // tau the next step with tau&3 == q

  const int k = ln & 3;    // K-chunk (h columns [32k, 32k+32))
  const int rl = ln >> 2;  // local row 0..15
  int rowk = 0, hwr = 0;   // kept row after quad reduce; padded write index
  bool wvalid = false;

  if (wv < 2) {
    const int rbase = 58 * wv;
    rowk = rbase + rl + 16 * k;
    wvalid = (rl + 16 * k) < 58;
    hwr = 36 * (rowk >> 5) + (rowk & 31);
#pragma unroll
    for (int p = 0; p < 4; ++p) {
      const int rloc = rl + 16 * p;
      const bool vr = rloc < 58;
      const size_t r = rbase + (vr ? rloc : 0);
#pragma unroll
      for (int j = 0; j < 32; ++j) {
        const int col = 32 * k + j;
        w[p][j] = (vr && col < kH) ? W_hh[r * kH + col] : 0.f;
      }
    }
  } else if (wv == 2) {
    rowk = rl + 16 * k;
#pragma unroll
    for (int p = 0; p < 4; ++p) {
      const int rloc = rl + 16 * p;
      const bool vr = rloc < kO;
      const size_t r = vr ? rloc : 0;
#pragma unroll
      for (int j = 0; j < 32; ++j) {
        const int col = 32 * k + j;
        w[p][j] = (vr && col < kH) ? W_fc[r * kH + col] : 0.f;
      }
    }
    bfc = (rowk < kO) ? b_fc[rowk] : 0.f;
  } else {
    {
      const float2* wr = (const float2*)(W_ih + ln * kI);  // 200B rows: 8B aligned
#pragma unroll
      for (int i = 0; i < kI / 2; ++i) {
        float2 v = wr[i]; wi0[2 * i] = v.x; wi0[2 * i + 1] = v.y;
      }
      bias0 = b_ih[ln] + b_hh[ln];
    }
    if (ln < kH - 64) {
      const float2* wr = (const float2*)(W_ih + (ln + 64) * kI);
#pragma unroll
      for (int i = 0; i < kI / 2; ++i) {
        float2 v = wr[i]; wi1[2 * i] = v.x; wi1[2 * i + 1] = v.y;
      }
      bias1 = b_ih[ln + 64] + b_hh[ln + 64];
    } else {
#pragma unroll
      for (int i = 0; i < kI; ++i) wi1[i] = 0.f;
    }
    if (ln < kI) {
#pragma unroll
      for (int q = 0; q < 4; ++q) xrv[q] = xb[(size_t)q * kI + ln];
    }
  }
  // Zero the ENTIRE h ring: h(-1)=0 at slot 15, and all pad positions in all
  // slots must be 0 forever (they multiply zero weights; 0*garbage = hazard).
  for (int z = tid; z < kHD * 144; z += 256) ((float*)sm.h)[z] = 0.f;
  if (tid == 0) { sm.flags[0] = -1; sm.flags[1] = -1; }
  sync_lds();  // barrier: init published

  if (wv < 2) __builtin_amdgcn_s_setprio(1);  // favor the recurrence waves

  // xp prologue: tau = 0..7 fills xp slots 0..7 so h can start at t=0.
  if (wv == 3) {
#pragma unroll
    for (int j = 0; j < kSS; ++j) {
      xp_step_rl(sm, j & (kXPD - 1), xrv[j & 3], wi0, wi1, bias0, bias1, ln);
      if (ln < kI) xrv[j & 3] = xb[(size_t)(j + 4) * kI + ln];  // j+4 <= 11
    }
  }
  sync_lds();  // barrier: xp[0..7] published

  volatile int* my = (volatile int*)&sm.flags[wv & 1];
  const volatile int* oth = (const volatile int*)&sm.flags[1 - (wv & 1)];

#pragma unroll 1
  for (int s = 0; s < kT / kSS; ++s) {
    if (wv < 2) {
      // 8 serial steps; speculative flag+data co-issue, no full barrier.
      const int t0 = kSS * s;
#pragma unroll
      for (int j = 0; j < kSS; ++j)
        h_step(sm, t0 + j, w, k, rowk, hwr, wvalid, j > 0, oth, my, ln);
    } else if (wv == 2) {
      // Lag one superstep: u in [8s-8, 8s-1]; all h[u] barrier-published.
      if (s > 0) {
        const int u0 = kSS * (s - 1);
#pragma unroll
        for (int j = 0; j < kSS; ++j)
          fc_step(sm, u0 + j, w, k, rowk, bfc, ob);
      }
    } else {
      // Lead one superstep: tau in [8s+8, 8s+15]; slots disjoint (mod 16)
      // from the h-waves' reads this superstep. tau0 % 4 == 0 -> tau&3 == j&3.
      if (s < kT / kSS - 1) {
        const int tau0 = kSS * s + kSS;
#pragma unroll
        for (int j = 0; j < kSS; ++j) {
          const int tau = tau0 + j;
          xp_step_rl(sm, tau & (kXPD - 1), xrv[j & 3], wi0, wi1, bias0, bias1,
                     ln);
          if (ln < kI) {
            int tf = tau + 4; tf = tf < kT ? tf : kT - 1;
            xrv[j & 3] = xb[(size_t)tf * kI + ln];
          }
        }
      }
    }
    sync_lds();  // one barrier per 8 steps
  }

  // fc epilogue: u = 2040..2047 (published by the final barrier).
  if (wv == 2) {
#pragma unroll
    for (int j = 0; j < kSS; ++j)
      fc_step(sm, kT - kSS + j, w, k, rowk, bfc, ob);
  }
}

extern "C" void kernel_launch(void* const* d_in, const int* in_sizes, int n_in,
                              void* d_out, int out_size, void* d_ws, size_t ws_size,
                              hipStream_t stream) {
  (void)in_sizes; (void)n_in; (void)d_ws; (void)ws_size; (void)out_size;
  const float* x    = (const float*)d_in[0];
  const float* W_ih = (const float*)d_in[1];
  const float* b_ih = (const float*)d_in[2];
  const float* W_hh = (const float*)d_in[3];
  const float* b_hh = (const float*)d_in[4];
  const float* W_fc = (const float*)d_in[5];
  const float* b_fc = (const float*)d_in[6];
  float* out = (float*)d_out;
  rnn_fused<<<dim3(kB), dim3(256), 0, stream>>>(x, W_ih, b_ih, W_hh, b_hh,
                                                W_fc, b_fc, out);
}